// Round 7
// baseline (282.668 us; speedup 1.0000x reference)
//
#include <hip/hip_runtime.h>
#include <cstdint>

#define Bn 128
#define Nn 4096
#define Dn 64
#define Kn 8
#define PBn 16
#define NCHUNKn (Nn / PBn)
#define LN_EPSf 1e-5f
#define EPSf 1e-8f

typedef unsigned short u16x8 __attribute__((ext_vector_type(8)));

static __device__ __forceinline__ uint16_t f2bf(float f) {
    union { float f; uint32_t u; } v; v.f = f;
    return (uint16_t)((v.u + 0x7fffu + ((v.u >> 16) & 1u)) >> 16);
}
static __device__ __forceinline__ float bflo(uint32_t u) {
    union { uint32_t u; float f; } v; v.u = u << 16; return v.f;
}
static __device__ __forceinline__ float bfhi(uint32_t u) {
    union { uint32_t u; float f; } v; v.u = u & 0xffff0000u; return v.f;
}

// DPP butterfly add: x += lane-permuted x.  Pure VALU, no DS pipe.
// ctrl: 0xB1 quad_perm ^1, 0x4E quad_perm ^2, 0x141 half_mirror,
//       0x128 row_ror:8.  (All validated in R3-R5.)
template <int CTRL>
static __device__ __forceinline__ float dppadd(float x) {
    int p = __builtin_amdgcn_update_dpp(0, __float_as_int(x), CTRL, 0xf, 0xf, false);
    return x + __int_as_float(p);
}

// ---------------- slot init: slots = mu + exp(ls)*noise ----------------
__global__ __launch_bounds__(256) void kinit(const float* __restrict__ noise,
                                             const float* __restrict__ mu,
                                             const float* __restrict__ ls,
                                             float* __restrict__ slots) {
    int i = blockIdx.x * 256 + threadIdx.x;
    int base = i * 4;
    int d = base & 63;
    float4 nz = *(const float4*)(noise + base);
    float4 m  = *(const float4*)(mu + d);
    float4 s  = *(const float4*)(ls + d);
    float4 o;
    o.x = m.x + __expf(s.x) * nz.x;
    o.y = m.y + __expf(s.y) * nz.y;
    o.z = m.z + __expf(s.z) * nz.z;
    o.w = m.w + __expf(s.w) * nz.w;
    *(float4*)(slots + base) = o;
}

// ---------------- kM: M = (Wq^T @ Wk) / sqrt(D) ----------------
__global__ __launch_bounds__(256) void kM(const float* __restrict__ Wq,
                                          const float* __restrict__ Wk,
                                          float* __restrict__ M) {
    const int idx = blockIdx.x * 256 + threadIdx.x;  // 4096
    const int e = idx >> 6, f = idx & 63;
    float acc = 0.f;
#pragma unroll 8
    for (int d = 0; d < 64; ++d) acc += Wq[d * 64 + e] * Wk[d * 64 + f];
    M[idx] = acc * 0.125f;
}

// ---------------- k1: x = LN(inputs) -> bf16 (pure streaming) ----------
__global__ __launch_bounds__(256) void k1_ln(const float* __restrict__ inp,
                                             const float* __restrict__ lng,
                                             const float* __restrict__ lnb,
                                             uint16_t* __restrict__ xout) {
    const int t = threadIdx.x;
    const long row = (long)blockIdx.x * 64 + (t >> 2);
    const int c0 = (t & 3) * 16;

    const float* src = inp + row * 64 + c0;
    float x[16];
#pragma unroll
    for (int u = 0; u < 4; ++u) {
        float4 v4 = *(const float4*)(src + u * 4);
        x[u * 4 + 0] = v4.x; x[u * 4 + 1] = v4.y;
        x[u * 4 + 2] = v4.z; x[u * 4 + 3] = v4.w;
    }
    float s1 = 0.f, s2 = 0.f;
#pragma unroll
    for (int i = 0; i < 16; ++i) { s1 += x[i]; s2 += x[i] * x[i]; }
    s1 = dppadd<0xB1>(s1); s2 = dppadd<0xB1>(s2);
    s1 = dppadd<0x4E>(s1); s2 = dppadd<0x4E>(s2);
    const float mean = s1 * (1.0f / 64.0f);
    const float var = s2 * (1.0f / 64.0f) - mean * mean;
    const float rstd = rsqrtf(var + LN_EPSf);

    u16x8 o0, o1;
#pragma unroll
    for (int i = 0; i < 8; ++i) {
        o0[i] = f2bf((x[i] - mean) * rstd * lng[c0 + i] + lnb[c0 + i]);
        o1[i] = f2bf((x[8 + i] - mean) * rstd * lng[c0 + 8 + i] + lnb[c0 + 8 + i]);
    }
    uint16_t* dst = xout + row * 64 + c0;
    *(u16x8*)dst = o0;
    *(u16x8*)(dst + 8) = o1;
}

// ---------------- k2: attention pass over an N-chunk -------------------
// grid = B*PBn (2048).  thread = (pg = t>>3 in [0,32), dc = t&7).  Reads
// only x.  ILP-2: two independent position chains per step; 2-deep global
// prefetch; no max-subtraction (logits bounded); v_rcp for 1/es.
__global__ __launch_bounds__(256) void k2_attn(
    const uint16_t* __restrict__ xbf, const float* __restrict__ slots,
    const float* __restrict__ M, const float* __restrict__ lsg,
    const float* __restrict__ lsb, float* __restrict__ partials) {
    __shared__ float sraw[Kn * Dn];
    __shared__ float sln[Kn][68];
    __shared__ float qld[Kn][64];
    __shared__ float red[16 * 552];   // [copy][kk*68 + d], padded strides
    __shared__ float redas[16][8];

    const int t = threadIdx.x;
    const int b = blockIdx.x >> 4;
    const int part = blockIdx.x & 15;

    if (t < 128) *(float4*)(sraw + t * 4) = *(const float4*)(slots + b * 512 + t * 4);
    __syncthreads();

    // LN over slot rows (16 lanes/row); DPP reduce (validated combo)
    if (t < 128) {
        const int row = t >> 4, l16 = t & 15;
        float4 v4 = *(const float4*)(sraw + row * 64 + l16 * 4);
        float s1 = v4.x + v4.y + v4.z + v4.w;
        float s2 = v4.x * v4.x + v4.y * v4.y + v4.z * v4.z + v4.w * v4.w;
        s1 = dppadd<0xB1>(s1); s2 = dppadd<0xB1>(s2);
        s1 = dppadd<0x4E>(s1); s2 = dppadd<0x4E>(s2);
        s1 = dppadd<0x141>(s1); s2 = dppadd<0x141>(s2);
        s1 = dppadd<0x128>(s1); s2 = dppadd<0x128>(s2);
        const float mean = s1 * (1.0f / 64.0f);
        const float var = s2 * (1.0f / 64.0f) - mean * mean;
        const float rstd = rsqrtf(var + LN_EPSf);
        const float xs[4] = {v4.x, v4.y, v4.z, v4.w};
#pragma unroll
        for (int i = 0; i < 4; ++i) {
            const int dcol = l16 * 4 + i;
            sln[row][dcol] = (xs[i] - mean) * rstd * lsg[dcol] + lsb[dcol];
        }
    }
    __syncthreads();

    // qk = sln @ M  (M folds 1/sqrt(D))
    {
        const int kk0 = t >> 6, kk1 = kk0 + 4;
        const int j = t & 63;
        float a0 = 0.f, a1 = 0.f;
#pragma unroll 8
        for (int e = 0; e < 64; ++e) {
            const float m = M[e * 64 + j];
            a0 += sln[kk0][e] * m;
            a1 += sln[kk1][e] * m;
        }
        qld[kk0][j] = a0;
        qld[kk1][j] = a1;
    }
    __syncthreads();

    const int dc = t & 7;
    const int pg = t >> 3;  // 0..31
    float qr[8][8];
#pragma unroll
    for (int kk = 0; kk < 8; ++kk) {
        float4 q0 = *(const float4*)&qld[kk][dc * 8];
        float4 q1 = *(const float4*)&qld[kk][dc * 8 + 4];
        qr[kk][0] = q0.x; qr[kk][1] = q0.y; qr[kk][2] = q0.z; qr[kk][3] = q0.w;
        qr[kk][4] = q1.x; qr[kk][5] = q1.y; qr[kk][6] = q1.z; qr[kk][7] = q1.w;
    }

    float upd[8][8];
    float asum[8];
#pragma unroll
    for (int kk = 0; kk < 8; ++kk) {
        asum[kk] = 0.f;
#pragma unroll
        for (int i = 0; i < 8; ++i) upd[kk][i] = 0.f;
    }

    const uint16_t* xbase = xbf + ((long)b * Nn + part * NCHUNKn) * 64 + dc * 8;

    uint4 xr0 = *(const uint4*)(xbase + (long)pg * 64);
    uint4 xr1 = *(const uint4*)(xbase + (long)(32 + pg) * 64);

#pragma unroll
    for (int it = 0; it < NCHUNKn / 64; ++it) {
        uint4 xn0 = xr0, xn1 = xr1;
        if (it < NCHUNKn / 64 - 1) {
            xn0 = *(const uint4*)(xbase + (long)((it + 1) * 64 + pg) * 64);
            xn1 = *(const uint4*)(xbase + (long)((it + 1) * 64 + 32 + pg) * 64);
        }
        float xf0[8], xf1[8];
        xf0[0] = bflo(xr0.x); xf0[1] = bfhi(xr0.x);
        xf0[2] = bflo(xr0.y); xf0[3] = bfhi(xr0.y);
        xf0[4] = bflo(xr0.z); xf0[5] = bfhi(xr0.z);
        xf0[6] = bflo(xr0.w); xf0[7] = bfhi(xr0.w);
        xf1[0] = bflo(xr1.x); xf1[1] = bfhi(xr1.x);
        xf1[2] = bflo(xr1.y); xf1[3] = bfhi(xr1.y);
        xf1[4] = bflo(xr1.z); xf1[5] = bfhi(xr1.z);
        xf1[6] = bflo(xr1.w); xf1[7] = bfhi(xr1.w);

        float lg0[8], lg1[8];
#pragma unroll
        for (int kk = 0; kk < 8; ++kk) {
            float a0 = 0.f, a1 = 0.f;
#pragma unroll
            for (int i = 0; i < 8; ++i) {
                a0 += qr[kk][i] * xf0[i];
                a1 += qr[kk][i] * xf1[i];
            }
            lg0[kk] = a0;
            lg1[kk] = a1;
        }
        // reduce over the 8 dc lanes (two independent chains interleave)
#pragma unroll
        for (int kk = 0; kk < 8; ++kk) { lg0[kk] = dppadd<0xB1>(lg0[kk]); lg1[kk] = dppadd<0xB1>(lg1[kk]); }
#pragma unroll
        for (int kk = 0; kk < 8; ++kk) { lg0[kk] = dppadd<0x4E>(lg0[kk]); lg1[kk] = dppadd<0x4E>(lg1[kk]); }
#pragma unroll
        for (int kk = 0; kk < 8; ++kk) { lg0[kk] = dppadd<0x141>(lg0[kk]); lg1[kk] = dppadd<0x141>(lg1[kk]); }
        // softmax over 8 slots, no max-subtraction (|logit| bounded ~19)
        float e0[8], e1[8];
        float es0 = 0.f, es1 = 0.f;
#pragma unroll
        for (int kk = 0; kk < 8; ++kk) {
            e0[kk] = __expf(lg0[kk]); es0 += e0[kk];
            e1[kk] = __expf(lg1[kk]); es1 += e1[kk];
        }
        const float r0 = __builtin_amdgcn_rcpf(es0);
        const float r1 = __builtin_amdgcn_rcpf(es1);
#pragma unroll
        for (int kk = 0; kk < 8; ++kk) {
            const float a0 = e0[kk] * r0;
            const float a1 = e1[kk] * r1;
            asum[kk] += a0 + a1;
#pragma unroll
            for (int i = 0; i < 8; ++i)
                upd[kk][i] += a0 * xf0[i] + a1 * xf1[i];
        }
        xr0 = xn0; xr1 = xn1;
    }

    // ---- tail: one DPP ror8 round (pairs pg within 16-lane rows) ----
#pragma unroll
    for (int kk = 0; kk < 8; ++kk) {
#pragma unroll
        for (int i = 0; i < 8; ++i) upd[kk][i] = dppadd<0x128>(upd[kk][i]);
        asum[kk] = dppadd<0x128>(asum[kk]);
    }
    const int l = t & 63;
    const int wv = t >> 6;
    if ((l & 8) == 0) {
        const int copy = wv * 4 + (l >> 4);
        float* rb = red + copy * 552 + (l & 7) * 8;
#pragma unroll
        for (int kk = 0; kk < 8; ++kk) {
            float4 u0, u1;
            u0.x = upd[kk][0]; u0.y = upd[kk][1]; u0.z = upd[kk][2]; u0.w = upd[kk][3];
            u1.x = upd[kk][4]; u1.y = upd[kk][5]; u1.z = upd[kk][6]; u1.w = upd[kk][7];
            *(float4*)(rb + kk * 68) = u0;
            *(float4*)(rb + kk * 68 + 4) = u1;
        }
        if ((l & 15) == 0) {
            float4 a0, a1;
            a0.x = asum[0]; a0.y = asum[1]; a0.z = asum[2]; a0.w = asum[3];
            a1.x = asum[4]; a1.y = asum[5]; a1.z = asum[6]; a1.w = asum[7];
            *(float4*)&redas[copy][0] = a0;
            *(float4*)&redas[copy][4] = a1;
        }
    }
    __syncthreads();
    float* pout = partials + (long)(b * PBn + part) * 520;
    if (t < 128) {
        const int kk = t >> 4, dq = t & 15;
        float4 acc = {0.f, 0.f, 0.f, 0.f};
#pragma unroll
        for (int c = 0; c < 16; ++c) {
            float4 v = *(const float4*)(red + c * 552 + kk * 68 + dq * 4);
            acc.x += v.x; acc.y += v.y; acc.z += v.z; acc.w += v.w;
        }
        *(float4*)(pout + kk * 64 + dq * 4) = acc;
    }
    if (t < 8) {
        float a = 0.f;
#pragma unroll
        for (int c = 0; c < 16; ++c) a += redas[c][t];
        pout[512 + t] = a;
    }
}

// ---------------- k3: per-(batch,slot) update: Wv + GRU + MLP ----------
__global__ __launch_bounds__(256) void k3_update(
    const float* __restrict__ partials, const float* __restrict__ slots_in,
    const float* __restrict__ Wv,
    const float* __restrict__ wih, const float* __restrict__ whh,
    const float* __restrict__ bih, const float* __restrict__ bhh,
    const float* __restrict__ mg, const float* __restrict__ mb,
    const float* __restrict__ w1, const float* __restrict__ b1,
    const float* __restrict__ w2, const float* __restrict__ b2,
    float* __restrict__ slots_out) {
    __shared__ float axn[64];
    __shared__ float updf[64];
    __shared__ float sp[64];
    __shared__ float gi[192];
    __shared__ float gh[192];
    __shared__ float sn[64];
    __shared__ float hln[64];
    __shared__ float hid[256];

    const int t = threadIdx.x;
    const int b = blockIdx.x >> 3;
    const int s = blockIdx.x & 7;
    const float* pp = partials + (long)b * PBn * 520;

    float asum = EPSf;
#pragma unroll
    for (int j = 0; j < PBn; ++j) asum += pp[j * 520 + 512 + s];
    const float rasum = 1.0f / asum;

    if (t < 64) {
        float a = 0.f;
#pragma unroll
        for (int j = 0; j < PBn; ++j) a += pp[j * 520 + s * 64 + t];
        axn[t] = a * rasum;
    } else if (t < 80) {
        const int i = t - 64;
        *(float4*)&sp[i * 4] = *(const float4*)(slots_in + b * 512 + s * 64 + i * 4);
    }
    __syncthreads();

    {
        const int d = t >> 2, h = t & 3;
        const float* wr = Wv + d * 64 + h * 16;
        float acc = 0.f;
#pragma unroll
        for (int u = 0; u < 4; ++u) {
            float4 w4 = *(const float4*)(wr + u * 4);
            float4 a4 = *(const float4*)&axn[h * 16 + u * 4];
            acc += w4.x * a4.x + w4.y * a4.y + w4.z * a4.z + w4.w * a4.w;
        }
        acc = dppadd<0xB1>(acc);
        acc = dppadd<0x4E>(acc);
        if (h == 0) updf[d] = acc;
    }
    __syncthreads();

    for (int w = t; w < 768; w += 256) {
        const int j = w >> 2, h = w & 3;
        const float* wr = wih + j * 64 + h * 16;
        float acc = 0.f;
#pragma unroll
        for (int u = 0; u < 4; ++u) {
            float4 w4 = *(const float4*)(wr + u * 4);
            float4 a4 = *(const float4*)&updf[h * 16 + u * 4];
            acc += w4.x * a4.x + w4.y * a4.y + w4.z * a4.z + w4.w * a4.w;
        }
        acc = dppadd<0xB1>(acc);
        acc = dppadd<0x4E>(acc);
        if (h == 0) gi[j] = acc + bih[j];
    }
    for (int w = t; w < 768; w += 256) {
        const int j = w >> 2, h = w & 3;
        const float* wr = whh + j * 64 + h * 16;
        float acc = 0.f;
#pragma unroll
        for (int u = 0; u < 4; ++u) {
            float4 w4 = *(const float4*)(wr + u * 4);
            float4 a4 = *(const float4*)&sp[h * 16 + u * 4];
            acc += w4.x * a4.x + w4.y * a4.y + w4.z * a4.z + w4.w * a4.w;
        }
        acc = dppadd<0xB1>(acc);
        acc = dppadd<0x4E>(acc);
        if (h == 0) gh[j] = acc + bhh[j];
    }
    __syncthreads();

    if (t < 64) {
        const float ir = gi[t], iz = gi[64 + t], in_ = gi[128 + t];
        const float hr = gh[t], hz = gh[64 + t], hn = gh[128 + t];
        const float r = 1.0f / (1.0f + __expf(-(ir + hr)));
        const float z = 1.0f / (1.0f + __expf(-(iz + hz)));
        const float n = tanhf(in_ + r * hn);
        sn[t] = (1.0f - z) * n + z * sp[t];
    }
    __syncthreads();

    if (t < 16) {
        float4 v4 = *(const float4*)&sn[t * 4];
        float s1 = v4.x + v4.y + v4.z + v4.w;
        float s2 = v4.x * v4.x + v4.y * v4.y + v4.z * v4.z + v4.w * v4.w;
        s1 = dppadd<0xB1>(s1); s2 = dppadd<0xB1>(s2);
        s1 = dppadd<0x4E>(s1); s2 = dppadd<0x4E>(s2);
        s1 = dppadd<0x141>(s1); s2 = dppadd<0x141>(s2);
        s1 = dppadd<0x128>(s1); s2 = dppadd<0x128>(s2);
        const float mean = s1 * (1.0f / 64.0f);
        const float var = s2 * (1.0f / 64.0f) - mean * mean;
        const float rstd = rsqrtf(var + LN_EPSf);
        const float xs[4] = {v4.x, v4.y, v4.z, v4.w};
#pragma unroll
        for (int i = 0; i < 4; ++i) {
            const int dcol = t * 4 + i;
            hln[dcol] = (xs[i] - mean) * rstd * mg[dcol] + mb[dcol];
        }
    }
    __syncthreads();

    for (int w = t; w < 1024; w += 256) {
        const int j = w >> 2, h = w & 3;
        const float* wr = w1 + j * 64 + h * 16;
        float acc = 0.f;
#pragma unroll
        for (int u = 0; u < 4; ++u) {
            float4 w4 = *(const float4*)(wr + u * 4);
            float4 a4 = *(const float4*)&hln[h * 16 + u * 4];
            acc += w4.x * a4.x + w4.y * a4.y + w4.z * a4.z + w4.w * a4.w;
        }
        acc = dppadd<0xB1>(acc);
        acc = dppadd<0x4E>(acc);
        if (h == 0) hid[j] = fmaxf(acc + b1[j], 0.0f);
    }
    __syncthreads();

    {
        const int d = t >> 2, h = t & 3;
        const float* wr = w2 + d * 256 + h * 64;
        float acc = 0.f;
#pragma unroll
        for (int u = 0; u < 16; ++u) {
            float4 w4 = *(const float4*)(wr + u * 4);
            float4 h4 = *(const float4*)&hid[h * 64 + u * 4];
            acc += w4.x * h4.x + w4.y * h4.y + w4.z * h4.z + w4.w * h4.w;
        }
        acc = dppadd<0xB1>(acc);
        acc = dppadd<0x4E>(acc);
        if (h == 0) slots_out[(long)b * 512 + s * 64 + d] = sn[d] + acc + b2[d];
    }
}

extern "C" void kernel_launch(void* const* d_in, const int* in_sizes, int n_in,
                              void* d_out, int out_size, void* d_ws, size_t ws_size,
                              hipStream_t stream) {
    const float* inputs = (const float*)d_in[0];
    const float* noise = (const float*)d_in[1];
    const float* mu = (const float*)d_in[2];
    const float* ls = (const float*)d_in[3];
    const float* Wq = (const float*)d_in[4];
    const float* Wk = (const float*)d_in[5];
    const float* Wv = (const float*)d_in[6];
    const float* wih = (const float*)d_in[7];
    const float* whh = (const float*)d_in[8];
    const float* bih = (const float*)d_in[9];
    const float* bhh = (const float*)d_in[10];
    const float* lng = (const float*)d_in[11];
    const float* lnb = (const float*)d_in[12];
    const float* lsg = (const float*)d_in[13];
    const float* lsb = (const float*)d_in[14];
    const float* mg = (const float*)d_in[15];
    const float* mb = (const float*)d_in[16];
    const float* w1 = (const float*)d_in[17];
    const float* b1 = (const float*)d_in[18];
    const float* w2 = (const float*)d_in[19];
    const float* b2 = (const float*)d_in[20];

    char* ws = (char*)d_ws;
    float* slots = (float*)ws;                                 // 256 KiB
    float* Mm = (float*)(ws + 262144);                         // 16 KiB
    uint16_t* xbf = (uint16_t*)(ws + 262144 + 16384);          // 64 MiB
    float* parts = (float*)(ws + 262144 + 16384 + (1 << 26));  // ~4.3 MiB

    kinit<<<64, 256, 0, stream>>>(noise, mu, ls, slots);
    kM<<<16, 256, 0, stream>>>(Wq, Wk, Mm);
    k1_ln<<<8192, 256, 0, stream>>>(inputs, lng, lnb, xbf);
    for (int it = 0; it < 3; ++it) {
        k2_attn<<<Bn * PBn, 256, 0, stream>>>(xbf, slots, Mm, lsg, lsb, parts);
        float* dst = (it == 2) ? (float*)d_out : slots;
        k3_update<<<Bn * Kn, 256, 0, stream>>>(parts, slots, Wv, wih, whh, bih, bhh,
                                               mg, mb, w1, b1, w2, b2, dst);
    }
}

// Round 8
// 202.103 us; speedup vs baseline: 1.3986x; 1.3986x over previous
//
#include <hip/hip_runtime.h>
#include <cstdint>

#define Bn 128
#define Nn 4096
#define Dn 64
#define Kn 8
#define PBn 8
#define NCHUNKn (Nn / PBn)
#define LN_EPSf 1e-5f
#define EPSf 1e-8f
#define LOG2Ef 1.4426950408889634f

typedef unsigned short u16x8 __attribute__((ext_vector_type(8)));

static __device__ __forceinline__ uint16_t f2bf(float f) {
    union { float f; uint32_t u; } v; v.f = f;
    return (uint16_t)((v.u + 0x7fffu + ((v.u >> 16) & 1u)) >> 16);
}
static __device__ __forceinline__ float bflo(uint32_t u) {
    union { uint32_t u; float f; } v; v.u = u << 16; return v.f;
}
static __device__ __forceinline__ float bfhi(uint32_t u) {
    union { uint32_t u; float f; } v; v.u = u & 0xffff0000u; return v.f;
}

// DPP butterfly add (validated R3-R7): 0xB1 ^1, 0x4E ^2, 0x141 ^7, 0x128 ror8.
template <int CTRL>
static __device__ __forceinline__ float dppadd(float x) {
    int p = __builtin_amdgcn_update_dpp(0, __float_as_int(x), CTRL, 0xf, 0xf, false);
    return x + __int_as_float(p);
}

// ---------------- kM: M = (Wq^T @ Wk) / sqrt(D) * log2(e) ----------------
__global__ __launch_bounds__(256) void kM(const float* __restrict__ Wq,
                                          const float* __restrict__ Wk,
                                          float* __restrict__ M) {
    const int idx = blockIdx.x * 256 + threadIdx.x;  // 4096
    const int e = idx >> 6, f = idx & 63;
    float acc = 0.f;
#pragma unroll 8
    for (int d = 0; d < 64; ++d) acc += Wq[d * 64 + e] * Wk[d * 64 + f];
    M[idx] = acc * 0.125f * LOG2Ef;
}

// ------- kinit_qk: slots = mu+exp(ls)*noise; qk0 = LN(slots)@M -----------
// grid = Bn.  Reuses the R5-validated slot-LN DPP + matvec code.
__global__ __launch_bounds__(256) void kinit_qk(
    const float* __restrict__ noise, const float* __restrict__ mu,
    const float* __restrict__ ls, const float* __restrict__ M,
    float* __restrict__ slots, float* __restrict__ qk) {
    __shared__ float sraw[Kn * Dn];
    __shared__ float sln[Kn][68];
    const int t = threadIdx.x;
    const int b = blockIdx.x;

    if (t < 128) {
        const int base = (b * 128 + t) * 4;
        const int d = base & 63;
        float4 nz = *(const float4*)(noise + base);
        float4 m4 = *(const float4*)(mu + d);
        float4 s4 = *(const float4*)(ls + d);
        float4 o;
        o.x = m4.x + __expf(s4.x) * nz.x;
        o.y = m4.y + __expf(s4.y) * nz.y;
        o.z = m4.z + __expf(s4.z) * nz.z;
        o.w = m4.w + __expf(s4.w) * nz.w;
        *(float4*)(slots + base) = o;
        *(float4*)(sraw + t * 4) = o;
    }
    __syncthreads();
    if (t < 128) {
        const int row = t >> 4, l16 = t & 15;
        float4 v4 = *(const float4*)(sraw + row * 64 + l16 * 4);
        float s1 = v4.x + v4.y + v4.z + v4.w;
        float s2 = v4.x * v4.x + v4.y * v4.y + v4.z * v4.z + v4.w * v4.w;
        s1 = dppadd<0xB1>(s1); s2 = dppadd<0xB1>(s2);
        s1 = dppadd<0x4E>(s1); s2 = dppadd<0x4E>(s2);
        s1 = dppadd<0x141>(s1); s2 = dppadd<0x141>(s2);
        s1 = dppadd<0x128>(s1); s2 = dppadd<0x128>(s2);
        const float mean = s1 * (1.0f / 64.0f);
        const float var = s2 * (1.0f / 64.0f) - mean * mean;
        const float rstd = rsqrtf(var + LN_EPSf);
        const float xs[4] = {v4.x, v4.y, v4.z, v4.w};
        // lsg/lsb are all-ones/zeros in setup but load them anyway via M? No:
        // they are inputs; handled below in a second pass (kept generic).
#pragma unroll
        for (int i = 0; i < 4; ++i) sln[row][l16 * 4 + i] = (xs[i] - mean) * rstd;
    }
    __syncthreads();
    // NOTE: slot-LN gamma/beta applied in the matvec input below.
    // (applied as sln*lsg+lsb inline; lsg/lsb passed via qk? -> see launch)
    // This kernel variant takes lsg/lsb folded: see kqk_apply below.
    // qk = (sln*lsg+lsb) @ M
    // lsg/lsb pointers are appended after qk in the arg list of the real
    // kernel; to keep one kernel we pass them here:
    // (implemented in kinit_qk2 below -- this body is completed there)
    ((void)0);
    // fallthrough: actual apply+matvec in this same kernel via extra params
    // -- see definition: we inline it here using globals passed in M's tail?
    // Simpler: this kernel is only used with lsg==1,lsb==0? NOT safe.
    // Real implementation below (kinit_qk_full).
}

// Full version with lsg/lsb (used; the one above is not launched).
__global__ __launch_bounds__(256) void kinit_qk_full(
    const float* __restrict__ noise, const float* __restrict__ mu,
    const float* __restrict__ ls, const float* __restrict__ M,
    const float* __restrict__ lsg, const float* __restrict__ lsb,
    float* __restrict__ slots, float* __restrict__ qk) {
    __shared__ float sraw[Kn * Dn];
    __shared__ float sln[Kn][68];
    const int t = threadIdx.x;
    const int b = blockIdx.x;

    if (t < 128) {
        const int base = (b * 128 + t) * 4;
        const int d = base & 63;
        float4 nz = *(const float4*)(noise + base);
        float4 m4 = *(const float4*)(mu + d);
        float4 s4 = *(const float4*)(ls + d);
        float4 o;
        o.x = m4.x + __expf(s4.x) * nz.x;
        o.y = m4.y + __expf(s4.y) * nz.y;
        o.z = m4.z + __expf(s4.z) * nz.z;
        o.w = m4.w + __expf(s4.w) * nz.w;
        *(float4*)(slots + base) = o;
        *(float4*)(sraw + t * 4) = o;
    }
    __syncthreads();
    if (t < 128) {
        const int row = t >> 4, l16 = t & 15;
        float4 v4 = *(const float4*)(sraw + row * 64 + l16 * 4);
        float s1 = v4.x + v4.y + v4.z + v4.w;
        float s2 = v4.x * v4.x + v4.y * v4.y + v4.z * v4.z + v4.w * v4.w;
        s1 = dppadd<0xB1>(s1); s2 = dppadd<0xB1>(s2);
        s1 = dppadd<0x4E>(s1); s2 = dppadd<0x4E>(s2);
        s1 = dppadd<0x141>(s1); s2 = dppadd<0x141>(s2);
        s1 = dppadd<0x128>(s1); s2 = dppadd<0x128>(s2);
        const float mean = s1 * (1.0f / 64.0f);
        const float var = s2 * (1.0f / 64.0f) - mean * mean;
        const float rstd = rsqrtf(var + LN_EPSf);
        const float xs[4] = {v4.x, v4.y, v4.z, v4.w};
#pragma unroll
        for (int i = 0; i < 4; ++i) {
            const int dcol = l16 * 4 + i;
            sln[row][dcol] = (xs[i] - mean) * rstd * lsg[dcol] + lsb[dcol];
        }
    }
    __syncthreads();
    // qk = sln @ M  (M folds 1/sqrt(D) and log2e); coalesced over j
    for (int o = t; o < 512; o += 256) {
        const int kk = o >> 6, j = o & 63;
        float a = 0.f;
#pragma unroll 8
        for (int e = 0; e < 64; ++e) a += sln[kk][e] * M[e * 64 + j];
        qk[b * 512 + o] = a;
    }
}

// ---------------- k1: x = LN(inputs) -> bf16 (pure streaming, R5) --------
__global__ __launch_bounds__(256) void k1_ln(const float* __restrict__ inp,
                                             const float* __restrict__ lng,
                                             const float* __restrict__ lnb,
                                             uint16_t* __restrict__ xout) {
    const int t = threadIdx.x;
    const long row = (long)blockIdx.x * 64 + (t >> 2);
    const int c0 = (t & 3) * 16;

    const float* src = inp + row * 64 + c0;
    float x[16];
#pragma unroll
    for (int u = 0; u < 4; ++u) {
        float4 v4 = *(const float4*)(src + u * 4);
        x[u * 4 + 0] = v4.x; x[u * 4 + 1] = v4.y;
        x[u * 4 + 2] = v4.z; x[u * 4 + 3] = v4.w;
    }
    float s1 = 0.f, s2 = 0.f;
#pragma unroll
    for (int i = 0; i < 16; ++i) { s1 += x[i]; s2 += x[i] * x[i]; }
    s1 = dppadd<0xB1>(s1); s2 = dppadd<0xB1>(s2);
    s1 = dppadd<0x4E>(s1); s2 = dppadd<0x4E>(s2);
    const float mean = s1 * (1.0f / 64.0f);
    const float var = s2 * (1.0f / 64.0f) - mean * mean;
    const float rstd = rsqrtf(var + LN_EPSf);

    u16x8 o0, o1;
#pragma unroll
    for (int i = 0; i < 8; ++i) {
        o0[i] = f2bf((x[i] - mean) * rstd * lng[c0 + i] + lnb[c0 + i]);
        o1[i] = f2bf((x[8 + i] - mean) * rstd * lng[c0 + 8 + i] + lnb[c0 + 8 + i]);
    }
    uint16_t* dst = xout + row * 64 + c0;
    *(u16x8*)dst = o0;
    *(u16x8*)(dst + 8) = o1;
}

// ---------------- k2: attention pass over an N-chunk (R5 core) ----------
// Preamble removed: qk loaded from global (2 KB).  exp2 direct (log2e in M),
// no max-subtraction + rcpf (R7-validated).
__global__ __launch_bounds__(256) void k2_attn(
    const uint16_t* __restrict__ xbf, const float* __restrict__ qkg,
    float* __restrict__ partials) {
    __shared__ float qld[Kn][64];
    __shared__ float red[16 * 552];
    __shared__ float redas[16][8];

    const int t = threadIdx.x;
    const int b = blockIdx.x >> 3;
    const int part = blockIdx.x & 7;

    if (t < 128) *(float4*)(&qld[0][0] + t * 4) = *(const float4*)(qkg + b * 512 + t * 4);
    __syncthreads();

    const int dc = t & 7;
    const int pg = t >> 3;  // 0..31
    float qr[8][8];
#pragma unroll
    for (int kk = 0; kk < 8; ++kk) {
        float4 q0 = *(const float4*)&qld[kk][dc * 8];
        float4 q1 = *(const float4*)&qld[kk][dc * 8 + 4];
        qr[kk][0] = q0.x; qr[kk][1] = q0.y; qr[kk][2] = q0.z; qr[kk][3] = q0.w;
        qr[kk][4] = q1.x; qr[kk][5] = q1.y; qr[kk][6] = q1.z; qr[kk][7] = q1.w;
    }

    float upd[8][8];
    float asum[8];
#pragma unroll
    for (int kk = 0; kk < 8; ++kk) {
        asum[kk] = 0.f;
#pragma unroll
        for (int i = 0; i < 8; ++i) upd[kk][i] = 0.f;
    }

    const uint16_t* xbase = xbf + ((long)b * Nn + part * NCHUNKn) * 64 + dc * 8;

    uint4 xr = *(const uint4*)(xbase + (long)pg * 64);

    for (int it = 0; it < NCHUNKn / 32; ++it) {
        uint4 xn = xr;
        if (it < NCHUNKn / 32 - 1)
            xn = *(const uint4*)(xbase + (long)((it + 1) * 32 + pg) * 64);
        float xf[8];
        xf[0] = bflo(xr.x); xf[1] = bfhi(xr.x);
        xf[2] = bflo(xr.y); xf[3] = bfhi(xr.y);
        xf[4] = bflo(xr.z); xf[5] = bfhi(xr.z);
        xf[6] = bflo(xr.w); xf[7] = bfhi(xr.w);

        float lg[8];
#pragma unroll
        for (int kk = 0; kk < 8; ++kk) {
            float a = 0.f;
#pragma unroll
            for (int i = 0; i < 8; ++i) a += qr[kk][i] * xf[i];
            lg[kk] = a;
        }
#pragma unroll
        for (int kk = 0; kk < 8; ++kk) lg[kk] = dppadd<0xB1>(lg[kk]);
#pragma unroll
        for (int kk = 0; kk < 8; ++kk) lg[kk] = dppadd<0x4E>(lg[kk]);
#pragma unroll
        for (int kk = 0; kk < 8; ++kk) lg[kk] = dppadd<0x141>(lg[kk]);
        // softmax over 8 slots: logits in log2 domain, bounded -> no max-sub
        float e[8];
        float es = 0.f;
#pragma unroll
        for (int kk = 0; kk < 8; ++kk) { e[kk] = exp2f(lg[kk]); es += e[kk]; }
        const float rinv = __builtin_amdgcn_rcpf(es);
#pragma unroll
        for (int kk = 0; kk < 8; ++kk) {
            const float a = e[kk] * rinv;
            asum[kk] += a;
#pragma unroll
            for (int i = 0; i < 8; ++i) upd[kk][i] += a * xf[i];
        }
        xr = xn;
    }

    // ---- tail: DPP ror8 pair-reduce, 16 copies -> LDS (R5-validated) ----
#pragma unroll
    for (int kk = 0; kk < 8; ++kk) {
#pragma unroll
        for (int i = 0; i < 8; ++i) upd[kk][i] = dppadd<0x128>(upd[kk][i]);
        asum[kk] = dppadd<0x128>(asum[kk]);
    }
    const int l = t & 63;
    const int wv = t >> 6;
    if ((l & 8) == 0) {
        const int copy = wv * 4 + (l >> 4);
        float* rb = red + copy * 552 + (l & 7) * 8;
#pragma unroll
        for (int kk = 0; kk < 8; ++kk) {
            float4 u0, u1;
            u0.x = upd[kk][0]; u0.y = upd[kk][1]; u0.z = upd[kk][2]; u0.w = upd[kk][3];
            u1.x = upd[kk][4]; u1.y = upd[kk][5]; u1.z = upd[kk][6]; u1.w = upd[kk][7];
            *(float4*)(rb + kk * 68) = u0;
            *(float4*)(rb + kk * 68 + 4) = u1;
        }
        if ((l & 15) == 0) {
            float4 a0, a1;
            a0.x = asum[0]; a0.y = asum[1]; a0.z = asum[2]; a0.w = asum[3];
            a1.x = asum[4]; a1.y = asum[5]; a1.z = asum[6]; a1.w = asum[7];
            *(float4*)&redas[copy][0] = a0;
            *(float4*)&redas[copy][4] = a1;
        }
    }
    __syncthreads();
    float* pout = partials + (long)(b * PBn + part) * 520;
    if (t < 128) {
        const int kk = t >> 4, dq = t & 15;
        float4 acc = {0.f, 0.f, 0.f, 0.f};
#pragma unroll
        for (int c = 0; c < 16; ++c) {
            float4 v = *(const float4*)(red + c * 552 + kk * 68 + dq * 4);
            acc.x += v.x; acc.y += v.y; acc.z += v.z; acc.w += v.w;
        }
        *(float4*)(pout + kk * 64 + dq * 4) = acc;
    }
    if (t < 8) {
        float a = 0.f;
#pragma unroll
        for (int c = 0; c < 16; ++c) a += redas[c][t];
        pout[512 + t] = a;
    }
}

// ---------------- k3: per-(batch,slot) update + next-iter qk row ---------
__global__ __launch_bounds__(256) void k3_update(
    const float* __restrict__ partials, const float* __restrict__ slots_in,
    const float* __restrict__ Wv,
    const float* __restrict__ wih, const float* __restrict__ whh,
    const float* __restrict__ bih, const float* __restrict__ bhh,
    const float* __restrict__ mg, const float* __restrict__ mb,
    const float* __restrict__ w1, const float* __restrict__ b1,
    const float* __restrict__ w2, const float* __restrict__ b2,
    const float* __restrict__ M, const float* __restrict__ lsg,
    const float* __restrict__ lsb,
    float* __restrict__ slots_out, float* __restrict__ qkout) {
    __shared__ float axn[64];
    __shared__ float updf[64];
    __shared__ float sp[64];
    __shared__ float gi[192];
    __shared__ float gh[192];
    __shared__ float sn[64];
    __shared__ float hln[64];
    __shared__ float hid[256];
    __shared__ float outv[64];
    __shared__ float lnq[64];

    const int t = threadIdx.x;
    const int b = blockIdx.x >> 3;
    const int s = blockIdx.x & 7;
    const float* pp = partials + (long)b * PBn * 520;

    float asum = EPSf;
#pragma unroll
    for (int j = 0; j < PBn; ++j) asum += pp[j * 520 + 512 + s];
    const float rasum = 1.0f / asum;

    if (t < 64) {
        float a = 0.f;
#pragma unroll
        for (int j = 0; j < PBn; ++j) a += pp[j * 520 + s * 64 + t];
        axn[t] = a * rasum;
    } else if (t < 80) {
        const int i = t - 64;
        *(float4*)&sp[i * 4] = *(const float4*)(slots_in + b * 512 + s * 64 + i * 4);
    }
    __syncthreads();

    {
        const int d = t >> 2, h = t & 3;
        const float* wr = Wv + d * 64 + h * 16;
        float acc = 0.f;
#pragma unroll
        for (int u = 0; u < 4; ++u) {
            float4 w4 = *(const float4*)(wr + u * 4);
            float4 a4 = *(const float4*)&axn[h * 16 + u * 4];
            acc += w4.x * a4.x + w4.y * a4.y + w4.z * a4.z + w4.w * a4.w;
        }
        acc = dppadd<0xB1>(acc);
        acc = dppadd<0x4E>(acc);
        if (h == 0) updf[d] = acc;
    }
    __syncthreads();

    for (int w = t; w < 768; w += 256) {
        const int j = w >> 2, h = w & 3;
        const float* wr = wih + j * 64 + h * 16;
        float acc = 0.f;
#pragma unroll
        for (int u = 0; u < 4; ++u) {
            float4 w4 = *(const float4*)(wr + u * 4);
            float4 a4 = *(const float4*)&updf[h * 16 + u * 4];
            acc += w4.x * a4.x + w4.y * a4.y + w4.z * a4.z + w4.w * a4.w;
        }
        acc = dppadd<0xB1>(acc);
        acc = dppadd<0x4E>(acc);
        if (h == 0) gi[j] = acc + bih[j];
    }
    for (int w = t; w < 768; w += 256) {
        const int j = w >> 2, h = w & 3;
        const float* wr = whh + j * 64 + h * 16;
        float acc = 0.f;
#pragma unroll
        for (int u = 0; u < 4; ++u) {
            float4 w4 = *(const float4*)(wr + u * 4);
            float4 a4 = *(const float4*)&sp[h * 16 + u * 4];
            acc += w4.x * a4.x + w4.y * a4.y + w4.z * a4.z + w4.w * a4.w;
        }
        acc = dppadd<0xB1>(acc);
        acc = dppadd<0x4E>(acc);
        if (h == 0) gh[j] = acc + bhh[j];
    }
    __syncthreads();

    if (t < 64) {
        const float ir = gi[t], iz = gi[64 + t], in_ = gi[128 + t];
        const float hr = gh[t], hz = gh[64 + t], hn = gh[128 + t];
        const float r = 1.0f / (1.0f + __expf(-(ir + hr)));
        const float z = 1.0f / (1.0f + __expf(-(iz + hz)));
        const float n = tanhf(in_ + r * hn);
        sn[t] = (1.0f - z) * n + z * sp[t];
    }
    __syncthreads();

    if (t < 16) {
        float4 v4 = *(const float4*)&sn[t * 4];
        float s1 = v4.x + v4.y + v4.z + v4.w;
        float s2 = v4.x * v4.x + v4.y * v4.y + v4.z * v4.z + v4.w * v4.w;
        s1 = dppadd<0xB1>(s1); s2 = dppadd<0xB1>(s2);
        s1 = dppadd<0x4E>(s1); s2 = dppadd<0x4E>(s2);
        s1 = dppadd<0x141>(s1); s2 = dppadd<0x141>(s2);
        s1 = dppadd<0x128>(s1); s2 = dppadd<0x128>(s2);
        const float mean = s1 * (1.0f / 64.0f);
        const float var = s2 * (1.0f / 64.0f) - mean * mean;
        const float rstd = rsqrtf(var + LN_EPSf);
        const float xs[4] = {v4.x, v4.y, v4.z, v4.w};
#pragma unroll
        for (int i = 0; i < 4; ++i) {
            const int dcol = t * 4 + i;
            hln[dcol] = (xs[i] - mean) * rstd * mg[dcol] + mb[dcol];
        }
    }
    __syncthreads();

    for (int w = t; w < 1024; w += 256) {
        const int j = w >> 2, h = w & 3;
        const float* wr = w1 + j * 64 + h * 16;
        float acc = 0.f;
#pragma unroll
        for (int u = 0; u < 4; ++u) {
            float4 w4 = *(const float4*)(wr + u * 4);
            float4 a4 = *(const float4*)&hln[h * 16 + u * 4];
            acc += w4.x * a4.x + w4.y * a4.y + w4.z * a4.z + w4.w * a4.w;
        }
        acc = dppadd<0xB1>(acc);
        acc = dppadd<0x4E>(acc);
        if (h == 0) hid[j] = fmaxf(acc + b1[j], 0.0f);
    }
    __syncthreads();

    {
        const int d = t >> 2, h = t & 3;
        const float* wr = w2 + d * 256 + h * 64;
        float acc = 0.f;
#pragma unroll
        for (int u = 0; u < 16; ++u) {
            float4 w4 = *(const float4*)(wr + u * 4);
            float4 h4 = *(const float4*)&hid[h * 64 + u * 4];
            acc += w4.x * h4.x + w4.y * h4.y + w4.z * h4.z + w4.w * h4.w;
        }
        acc = dppadd<0xB1>(acc);
        acc = dppadd<0x4E>(acc);
        if (h == 0) {
            const float val = sn[d] + acc + b2[d];
            slots_out[(long)b * 512 + s * 64 + d] = val;
            outv[d] = val;
        }
    }
    __syncthreads();

    // ---- next-iter qk row: LN(outv)*lsg+lsb @ M ----
    if (t < 16) {
        float4 v4 = *(const float4*)&outv[t * 4];
        float s1 = v4.x + v4.y + v4.z + v4.w;
        float s2 = v4.x * v4.x + v4.y * v4.y + v4.z * v4.z + v4.w * v4.w;
        s1 = dppadd<0xB1>(s1); s2 = dppadd<0xB1>(s2);
        s1 = dppadd<0x4E>(s1); s2 = dppadd<0x4E>(s2);
        s1 = dppadd<0x141>(s1); s2 = dppadd<0x141>(s2);
        s1 = dppadd<0x128>(s1); s2 = dppadd<0x128>(s2);
        const float mean = s1 * (1.0f / 64.0f);
        const float var = s2 * (1.0f / 64.0f) - mean * mean;
        const float rstd = rsqrtf(var + LN_EPSf);
        const float xs[4] = {v4.x, v4.y, v4.z, v4.w};
#pragma unroll
        for (int i = 0; i < 4; ++i) {
            const int dcol = t * 4 + i;
            lnq[dcol] = (xs[i] - mean) * rstd * lsg[dcol] + lsb[dcol];
        }
    }
    __syncthreads();
    if (t < 64) {
        float a = 0.f;
#pragma unroll 8
        for (int e = 0; e < 64; ++e) a += lnq[e] * M[e * 64 + t];
        qkout[b * 512 + s * 64 + t] = a;
    }
}

extern "C" void kernel_launch(void* const* d_in, const int* in_sizes, int n_in,
                              void* d_out, int out_size, void* d_ws, size_t ws_size,
                              hipStream_t stream) {
    const float* inputs = (const float*)d_in[0];
    const float* noise = (const float*)d_in[1];
    const float* mu = (const float*)d_in[2];
    const float* ls = (const float*)d_in[3];
    const float* Wq = (const float*)d_in[4];
    const float* Wk = (const float*)d_in[5];
    const float* Wv = (const float*)d_in[6];
    const float* wih = (const float*)d_in[7];
    const float* whh = (const float*)d_in[8];
    const float* bih = (const float*)d_in[9];
    const float* bhh = (const float*)d_in[10];
    const float* lng = (const float*)d_in[11];
    const float* lnb = (const float*)d_in[12];
    const float* lsg = (const float*)d_in[13];
    const float* lsb = (const float*)d_in[14];
    const float* mg = (const float*)d_in[15];
    const float* mb = (const float*)d_in[16];
    const float* w1 = (const float*)d_in[17];
    const float* b1 = (const float*)d_in[18];
    const float* w2 = (const float*)d_in[19];
    const float* b2 = (const float*)d_in[20];

    char* ws = (char*)d_ws;
    float* slots = (float*)ws;                                   // 256 KiB
    float* Mm = (float*)(ws + 262144);                           // 16 KiB
    float* qk = (float*)(ws + 262144 + 16384);                   // 256 KiB
    uint16_t* xbf = (uint16_t*)(ws + 262144 + 16384 + 262144);   // 64 MiB
    float* parts = (float*)(ws + 262144 + 16384 + 262144 + (1 << 26));  // ~2.2 MiB

    kM<<<16, 256, 0, stream>>>(Wq, Wk, Mm);
    kinit_qk_full<<<Bn, 256, 0, stream>>>(noise, mu, ls, Mm, lsg, lsb, slots, qk);
    k1_ln<<<8192, 256, 0, stream>>>(inputs, lng, lnb, xbf);
    for (int it = 0; it < 3; ++it) {
        k2_attn<<<Bn * PBn, 256, 0, stream>>>(xbf, qk, parts);
        float* dst = (it == 2) ? (float*)d_out : slots;
        k3_update<<<Bn * Kn, 256, 0, stream>>>(parts, slots, Wv, wih, whh, bih, bhh,
                                               mg, mb, w1, b1, w2, b2, Mm, lsg, lsb,
                                               dst, qk);
    }
}